// Round 19
// baseline (134.044 us; speedup 1.0000x reference)
//
#include <hip/hip_runtime.h>

#define H 128
#define KE 16
#define TILE (256 * KE)    // bin: 4096 edges/block
#define LINB 512           // linear blocks per half
#define NSUBMAX 784        // LDS bin count (>= ceil(N/128) = 782)
#define SCAP 3072          // per-sub-bucket capacity (avg 2048, +22 sigma)

typedef __attribute__((ext_vector_type(8))) short short8_t;   // 8 bf16
typedef __attribute__((ext_vector_type(4))) float float4_t;

__device__ __forceinline__ ushort f2bf(float f) {
  uint u = __float_as_uint(f);
  u += 0x7fff + ((u >> 16) & 1);          // RNE
  return (ushort)(u >> 16);
}
__device__ __forceinline__ float bflo(uint v) { return __uint_as_float(v << 16); }
__device__ __forceinline__ float bfhi(uint v) { return __uint_as_float(v & 0xffff0000u); }

// ---------- linear tile range: hs = bf16(x @ W^T) UNSCALED, LDS-free swapped MFMA ----------
__device__ __forceinline__ void linear_range(const float* __restrict__ x, const float* __restrict__ W,
                                             ushort* __restrict__ hs, int N,
                                             int tile0, int tend, int tid) {
  const int lane = tid & 63;
  const int wid  = tid >> 6;
  const int rg   = wid >> 1;
  const int cg   = wid & 1;
  const int q    = lane >> 4;
  const int lm   = lane & 15;

  short8_t bfr[4][4];
  #pragma unroll
  for (int kk = 0; kk < 4; ++kk) {
    #pragma unroll
    for (int nf = 0; nf < 4; ++nf) {
      const float* wp = W + (cg * 64 + nf * 16 + lm) * 128 + kk * 32 + q * 8;
      float4_t w0 = *(const float4_t*)wp;
      float4_t w1 = *(const float4_t*)(wp + 4);
      union { short8_t s; ushort u[8]; } t;
      t.u[0] = f2bf(w0.x); t.u[1] = f2bf(w0.y); t.u[2] = f2bf(w0.z); t.u[3] = f2bf(w0.w);
      t.u[4] = f2bf(w1.x); t.u[5] = f2bf(w1.y); t.u[6] = f2bf(w1.z); t.u[7] = f2bf(w1.w);
      bfr[kk][nf] = t.s;
    }
  }

  for (int tile = tile0; tile < tend; tile += LINB) {
    const int n0 = tile * 32;
    const int arow = n0 + rg * 16 + lm;
    const int arow_c = (arow < N) ? arow : (N - 1);
    const float* xp = x + (long)arow_c * H + q * 8;
    short8_t afr[4];
    #pragma unroll
    for (int kk = 0; kk < 4; ++kk) {
      float4_t x0 = *(const float4_t*)(xp + kk * 32);
      float4_t x1 = *(const float4_t*)(xp + kk * 32 + 4);
      union { short8_t s; ushort u[8]; } t;
      t.u[0] = f2bf(x0.x); t.u[1] = f2bf(x0.y); t.u[2] = f2bf(x0.z); t.u[3] = f2bf(x0.w);
      t.u[4] = f2bf(x1.x); t.u[5] = f2bf(x1.y); t.u[6] = f2bf(x1.z); t.u[7] = f2bf(x1.w);
      afr[kk] = t.s;
    }

    float4_t acc[4];
    #pragma unroll
    for (int nf = 0; nf < 4; ++nf) acc[nf] = (float4_t){0.f, 0.f, 0.f, 0.f};
    #pragma unroll
    for (int kk = 0; kk < 4; ++kk) {
      #pragma unroll
      for (int nf = 0; nf < 4; ++nf)
        acc[nf] = __builtin_amdgcn_mfma_f32_16x16x32_bf16(bfr[kk][nf], afr[kk], acc[nf], 0, 0, 0);
    }

    if (arow < N) {
      ushort* hrow = hs + (size_t)arow * H + cg * 64 + q * 4;
      #pragma unroll
      for (int nf = 0; nf < 4; ++nf) {
        uint2 o;
        o.x = (uint)f2bf(acc[nf][0]) | ((uint)f2bf(acc[nf][1]) << 16);
        o.y = (uint)f2bf(acc[nf][2]) | ((uint)f2bf(acc[nf][3]) << 16);
        *(uint2*)(hrow + nf * 16) = o;
      }
    }
  }
}

// ---------- kernel 1: [single-level bin (blocks 0..nbin-1)] || [linear half-A] ----------
__global__ __launch_bounds__(256) void k_binlinA(const int* __restrict__ src, const int* __restrict__ dst,
                                                 int* cur2, int* __restrict__ bsub, int E, int nsubt, int nbin,
                                                 const float* __restrict__ x, const float* __restrict__ W,
                                                 ushort* __restrict__ hs, int N, int tsplit) {
  __shared__ int cnt[NSUBMAX];
  __shared__ int lbase[NSUBMAX];
  __shared__ int gbase[NSUBMAX];
  __shared__ int ls[256];
  __shared__ int staged[TILE];
  __shared__ ushort sstage[TILE];
  const int tid = threadIdx.x;

  if (blockIdx.x >= nbin) {
    linear_range(x, W, hs, N, blockIdx.x - nbin, tsplit, tid);   // tiles [b, tsplit) stride LINB
    return;
  }

  // ===== single-level bin: edges -> bsub sub-bucket slots =====
  for (int i = tid; i < NSUBMAX; i += 256) cnt[i] = 0;
  __syncthreads();

  const int base = blockIdx.x * TILE;
  int pk[KE], off[KE];
  short sd[KE];
  #pragma unroll
  for (int k = 0; k < KE; ++k) {
    const int e = base + k * 256 + tid;
    if (e < E) {
      const int s = src[e], d = dst[e];
      const int sid = d >> 7;
      pk[k] = (s << 7) | (d & 127);
      sd[k] = (short)sid;
      off[k] = atomicAdd(&cnt[sid], 1);
    } else sd[k] = -1;
  }
  __syncthreads();

  // scan 784 bins: thread t owns bins [4t, 4t+4)
  int tsum = 0;
  if (tid < NSUBMAX / 4) {
    #pragma unroll
    for (int j = 0; j < 4; ++j) tsum += cnt[4 * tid + j];
  }
  ls[tid] = tsum;
  __syncthreads();
  for (int o = 1; o < 256; o <<= 1) {
    int v = (tid >= o) ? ls[tid - o] : 0;
    __syncthreads();
    ls[tid] += v;
    __syncthreads();
  }
  const int tot = ls[255];
  if (tid < NSUBMAX / 4) {
    int b = ls[tid] - tsum;   // exclusive
    #pragma unroll
    for (int j = 0; j < 4; ++j) { lbase[4 * tid + j] = b; b += cnt[4 * tid + j]; }
  }
  __syncthreads();
  for (int i = tid; i < nsubt; i += 256) {
    const int c = cnt[i];
    gbase[i] = c ? atomicAdd(&cur2[i], c) : 0;
  }
  __syncthreads();
  #pragma unroll
  for (int k = 0; k < KE; ++k) {
    if (sd[k] >= 0) {
      const int p = lbase[sd[k]] + off[k];
      staged[p] = pk[k];
      sstage[p] = (ushort)sd[k];
    }
  }
  __syncthreads();
  for (int i = tid; i < tot; i += 256) {
    const int sid = sstage[i];
    const int p = gbase[sid] + (i - lbase[sid]);
    if (p < SCAP) bsub[(size_t)sid * SCAP + p] = staged[i];
  }
}

// ---------- kernel 2: [fill3 (blocks 0..nsubt-1)] || [linear half-B] ----------
__global__ __launch_bounds__(256) void k_fill3linB(const int* __restrict__ bsub, const int* __restrict__ cur2,
                                                   float* __restrict__ dinv, uint4* __restrict__ rowinfo,
                                                   int* __restrict__ csr, int N, int nsubt,
                                                   const float* __restrict__ x, const float* __restrict__ W,
                                                   ushort* __restrict__ hs, int tsplit, int ntiles) {
  __shared__ int cnt[128], pre[128], lcur[128];
  __shared__ int stage[SCAP], sorted[SCAP];
  const int tid = threadIdx.x;

  if (blockIdx.x >= nsubt) {
    linear_range(x, W, hs, N, tsplit + (blockIdx.x - nsubt), ntiles, tid);
    return;
  }

  const int sid = blockIdx.x;
  const int gn0 = sid * 128;
  int nodes = N - gn0; if (nodes > 128) nodes = 128;
  if (nodes <= 0) return;
  if (tid < 128) cnt[tid] = 0;
  __syncthreads();

  const int slotbase = sid * SCAP;
  const int cc = min(cur2[sid], SCAP);
  const int* bp = bsub + (size_t)slotbase;
  for (int i = tid; i < cc; i += 256) {
    const int v = bp[i];
    stage[i] = v;
    atomicAdd(&cnt[v & 127], 1);
  }
  __syncthreads();

  // exclusive scan of cnt[128]
  if (tid < 128) pre[tid] = cnt[tid];
  __syncthreads();
  for (int off = 1; off < 128; off <<= 1) {
    int v = 0;
    if (tid < 128 && tid >= off) v = pre[tid - off];
    __syncthreads();
    if (tid < 128) pre[tid] += v;
    __syncthreads();
  }
  if (tid < 128) pre[tid] -= cnt[tid];
  __syncthreads();

  // per-node outputs
  if (tid < nodes) {
    const int c = cnt[tid];
    const float dv = rsqrtf((float)(1 + c));
    dinv[gn0 + tid] = dv;
    rowinfo[gn0 + tid] = make_uint4((uint)(slotbase + pre[tid]), (uint)c, __float_as_uint(dv), 0u);
    lcur[tid] = pre[tid];
  }
  __syncthreads();

  // counting sort stage -> sorted (src values)
  for (int i = tid; i < cc; i += 256) {
    const int v = stage[i];
    const int p = atomicAdd(&lcur[v & 127], 1);
    sorted[p] = (int)((unsigned)v >> 7);
  }
  __syncthreads();
  for (int i = tid; i < cc; i += 256) csr[slotbase + i] = sorted[i];
}

// ---------- aggregation: one node per 16-lane group; per-message dinv[s] fma ----------
#define ACCS(q, ds) { a0 = fmaf(bflo((q).x), ds, a0); a1 = fmaf(bfhi((q).x), ds, a1); \
                      a2 = fmaf(bflo((q).y), ds, a2); a3 = fmaf(bfhi((q).y), ds, a3); \
                      a4 = fmaf(bflo((q).z), ds, a4); a5 = fmaf(bfhi((q).z), ds, a5); \
                      a6 = fmaf(bflo((q).w), ds, a6); a7 = fmaf(bfhi((q).w), ds, a7); }
__global__ __launch_bounds__(256) void k_agg(const ushort* __restrict__ hs, const float* __restrict__ dinv,
                                             const uint4* __restrict__ rowinfo, const int* __restrict__ csr,
                                             const float* __restrict__ bias, float* __restrict__ out, int N) {
  const int d = blockIdx.x * 16 + (threadIdx.x >> 4);
  if (d >= N) return;
  const int j = threadIdx.x & 15;
  const uint4* hp = (const uint4*)hs;

  const uint4 info = rowinfo[d];
  int i = (int)info.x;
  int cnt = (int)info.y;
  const float dd = __uint_as_float(info.z);

  // self message: h[d]*dinv[d] (then *dd at the end)
  const uint4 qs = hp[(size_t)d * 16 + j];
  float a0 = bflo(qs.x) * dd, a1 = bfhi(qs.x) * dd, a2 = bflo(qs.y) * dd, a3 = bfhi(qs.y) * dd;
  float a4 = bflo(qs.z) * dd, a5 = bfhi(qs.z) * dd, a6 = bflo(qs.w) * dd, a7 = bfhi(qs.w) * dd;

  for (; cnt >= 8; cnt -= 8, i += 8) {
    const int s0 = csr[i],     s1 = csr[i + 1], s2 = csr[i + 2], s3 = csr[i + 3];
    const int s4 = csr[i + 4], s5 = csr[i + 5], s6 = csr[i + 6], s7 = csr[i + 7];
    const float d0 = dinv[s0], d1 = dinv[s1], d2 = dinv[s2], d3 = dinv[s3];
    const float d4 = dinv[s4], d5 = dinv[s5], d6 = dinv[s6], d7 = dinv[s7];
    const uint4 qA = hp[(size_t)s0 * 16 + j];
    const uint4 qB = hp[(size_t)s1 * 16 + j];
    const uint4 qC = hp[(size_t)s2 * 16 + j];
    const uint4 qD = hp[(size_t)s3 * 16 + j];
    const uint4 qE = hp[(size_t)s4 * 16 + j];
    const uint4 qF = hp[(size_t)s5 * 16 + j];
    const uint4 qG = hp[(size_t)s6 * 16 + j];
    const uint4 qH = hp[(size_t)s7 * 16 + j];
    ACCS(qA, d0) ACCS(qB, d1) ACCS(qC, d2) ACCS(qD, d3)
    ACCS(qE, d4) ACCS(qF, d5) ACCS(qG, d6) ACCS(qH, d7)
  }
  if (cnt >= 4) {
    const int s0 = csr[i], s1 = csr[i + 1], s2 = csr[i + 2], s3 = csr[i + 3];
    const float d0 = dinv[s0], d1 = dinv[s1], d2 = dinv[s2], d3 = dinv[s3];
    const uint4 qA = hp[(size_t)s0 * 16 + j];
    const uint4 qB = hp[(size_t)s1 * 16 + j];
    const uint4 qC = hp[(size_t)s2 * 16 + j];
    const uint4 qD = hp[(size_t)s3 * 16 + j];
    ACCS(qA, d0) ACCS(qB, d1) ACCS(qC, d2) ACCS(qD, d3)
    cnt -= 4; i += 4;
  }
  for (; cnt > 0; --cnt, ++i) {
    const int s = csr[i];
    const float ds = dinv[s];
    const uint4 q = hp[(size_t)s * 16 + j];
    ACCS(q, ds)
  }

  const float4_t b0 = *(const float4_t*)(bias + j * 8);
  const float4_t b1 = *(const float4_t*)(bias + j * 8 + 4);
  float4_t o0, o1;
  o0.x = a0 * dd + b0.x; o0.y = a1 * dd + b0.y; o0.z = a2 * dd + b0.z; o0.w = a3 * dd + b0.w;
  o1.x = a4 * dd + b1.x; o1.y = a5 * dd + b1.y; o1.z = a6 * dd + b1.z; o1.w = a7 * dd + b1.w;
  __builtin_nontemporal_store(o0, (float4_t*)(out + (size_t)d * H + j * 8));
  __builtin_nontemporal_store(o1, (float4_t*)(out + (size_t)d * H + j * 8 + 4));
}

extern "C" void kernel_launch(void* const* d_in, const int* in_sizes, int n_in,
                              void* d_out, int out_size, void* d_ws, size_t ws_size,
                              hipStream_t stream) {
  const float* x = (const float*)d_in[0];
  const int*   edge = (const int*)d_in[1];
  const float* W = (const float*)d_in[2];
  const float* b = (const float*)d_in[3];
  float* out = (float*)d_out;

  const int N = in_sizes[0] / H;     // 100000
  const int E = in_sizes[1] / 2;     // 1600000
  const int* src = edge;
  const int* dst = edge + E;
  const int nsubt = (N + 127) / 128;                // 782
  const int ntiles = (N + 31) / 32;                 // 3125
  const int tsplit = (ntiles + 1) / 2;              // 1563

  // workspace layout
  char* w = (char*)d_ws;
  ushort* hs     = (ushort*)w;  w += (size_t)N * H * 2;              // 25.6 MB
  float*  dinv   = (float*)w;   w += (size_t)N * 4;
  int*    cur2   = (int*)w;     w += (size_t)NSUBMAX * 4;
  uint4*  rowinfo= (uint4*)w;   w += (size_t)N * 16;                 // 1.6 MB
  int*    csr    = (int*)w;     w += (size_t)nsubt * SCAP * 4;       // 9.6 MB
  int*    bsub   = (int*)w;     w += (size_t)nsubt * SCAP * 4;       // 9.6 MB
  (void)ws_size;

  (void)hipMemsetAsync(cur2, 0, (size_t)NSUBMAX * 4, stream);

  const int nbin = (E + TILE - 1) / TILE;          // 391
  k_binlinA<<<nbin + LINB, 256, 0, stream>>>(src, dst, cur2, bsub, E, nsubt, nbin, x, W, hs, N, tsplit);
  k_fill3linB<<<nsubt + LINB, 256, 0, stream>>>(bsub, cur2, dinv, rowinfo, csr, N, nsubt,
                                                x, W, hs, tsplit, ntiles);
  k_agg<<<(N + 15) / 16, 256, 0, stream>>>(hs, dinv, rowinfo, csr, b, out, N);
}

// Round 20
// 122.067 us; speedup vs baseline: 1.0981x; 1.0981x over previous
//
#include <hip/hip_runtime.h>

#define H 128
#define KE 16
#define TILE (256 * KE)    // bin: 4096 edges/block
#define LINB 512           // linear blocks in fused kernel
#define NSUBMAX 784        // LDS bin count (>= ceil(N/128) = 782)
#define SCAP 3072          // per-sub-bucket capacity (avg 2048, +22 sigma)

typedef __attribute__((ext_vector_type(8))) short short8_t;   // 8 bf16
typedef __attribute__((ext_vector_type(4))) float float4_t;

__device__ __forceinline__ ushort f2bf(float f) {
  uint u = __float_as_uint(f);
  u += 0x7fff + ((u >> 16) & 1);          // RNE
  return (ushort)(u >> 16);
}
__device__ __forceinline__ float bflo(uint v) { return __uint_as_float(v << 16); }
__device__ __forceinline__ float bfhi(uint v) { return __uint_as_float(v & 0xffff0000u); }

// ---------- fused phase A: [linear (blocks 0..LINB-1)] || [single-level bin (blocks LINB..)] ----------
// linear: hs = bf16(x @ W^T) UNSCALED (dinv applied per-message in k_agg).
// bin: edges -> 782 sub-buckets DIRECTLY (784-bin LDS histogram + scan + dense run writes).
__global__ __launch_bounds__(256) void k_linbin(const float* __restrict__ x, const float* __restrict__ W,
                                                ushort* __restrict__ hs,
                                                const int* __restrict__ src, const int* __restrict__ dst,
                                                int* cur2, int* __restrict__ bsub,
                                                int N, int E, int nsubt) {
  __shared__ int cnt[NSUBMAX];
  __shared__ int lbase[NSUBMAX];
  __shared__ int gbase[NSUBMAX];
  __shared__ int ls[256];
  __shared__ int staged[TILE];
  __shared__ ushort sstage[TILE];
  const int tid = threadIdx.x;

  if (blockIdx.x < LINB) {
    // ===== linear (LDS-free, swapped MFMA) =====
    const int lane = tid & 63;
    const int wid  = tid >> 6;
    const int rg   = wid >> 1;
    const int cg   = wid & 1;
    const int q    = lane >> 4;
    const int lm   = lane & 15;

    short8_t bfr[4][4];
    #pragma unroll
    for (int kk = 0; kk < 4; ++kk) {
      #pragma unroll
      for (int nf = 0; nf < 4; ++nf) {
        const float* wp = W + (cg * 64 + nf * 16 + lm) * 128 + kk * 32 + q * 8;
        float4_t w0 = *(const float4_t*)wp;
        float4_t w1 = *(const float4_t*)(wp + 4);
        union { short8_t s; ushort u[8]; } t;
        t.u[0] = f2bf(w0.x); t.u[1] = f2bf(w0.y); t.u[2] = f2bf(w0.z); t.u[3] = f2bf(w0.w);
        t.u[4] = f2bf(w1.x); t.u[5] = f2bf(w1.y); t.u[6] = f2bf(w1.z); t.u[7] = f2bf(w1.w);
        bfr[kk][nf] = t.s;
      }
    }

    const int ntiles = (N + 31) / 32;
    for (int tile = blockIdx.x; tile < ntiles; tile += LINB) {
      const int n0 = tile * 32;
      const int arow = n0 + rg * 16 + lm;
      const int arow_c = (arow < N) ? arow : (N - 1);
      const float* xp = x + (long)arow_c * H + q * 8;
      short8_t afr[4];
      #pragma unroll
      for (int kk = 0; kk < 4; ++kk) {
        float4_t x0 = *(const float4_t*)(xp + kk * 32);
        float4_t x1 = *(const float4_t*)(xp + kk * 32 + 4);
        union { short8_t s; ushort u[8]; } t;
        t.u[0] = f2bf(x0.x); t.u[1] = f2bf(x0.y); t.u[2] = f2bf(x0.z); t.u[3] = f2bf(x0.w);
        t.u[4] = f2bf(x1.x); t.u[5] = f2bf(x1.y); t.u[6] = f2bf(x1.z); t.u[7] = f2bf(x1.w);
        afr[kk] = t.s;
      }

      float4_t acc[4];
      #pragma unroll
      for (int nf = 0; nf < 4; ++nf) acc[nf] = (float4_t){0.f, 0.f, 0.f, 0.f};
      #pragma unroll
      for (int kk = 0; kk < 4; ++kk) {
        #pragma unroll
        for (int nf = 0; nf < 4; ++nf)
          acc[nf] = __builtin_amdgcn_mfma_f32_16x16x32_bf16(bfr[kk][nf], afr[kk], acc[nf], 0, 0, 0);
      }

      if (arow < N) {
        ushort* hrow = hs + (size_t)arow * H + cg * 64 + q * 4;
        #pragma unroll
        for (int nf = 0; nf < 4; ++nf) {
          uint2 o;
          o.x = (uint)f2bf(acc[nf][0]) | ((uint)f2bf(acc[nf][1]) << 16);
          o.y = (uint)f2bf(acc[nf][2]) | ((uint)f2bf(acc[nf][3]) << 16);
          *(uint2*)(hrow + nf * 16) = o;
        }
      }
    }
  } else {
    // ===== single-level bin: edges -> bsub sub-bucket slots =====
    const int bb = blockIdx.x - LINB;
    for (int i = tid; i < NSUBMAX; i += 256) cnt[i] = 0;
    __syncthreads();

    const int base = bb * TILE;
    int pk[KE], off[KE];
    short sd[KE];
    #pragma unroll
    for (int k = 0; k < KE; ++k) {
      const int e = base + k * 256 + tid;
      if (e < E) {
        const int s = src[e], d = dst[e];
        const int sid = d >> 7;
        pk[k] = (s << 7) | (d & 127);
        sd[k] = (short)sid;
        off[k] = atomicAdd(&cnt[sid], 1);
      } else sd[k] = -1;
    }
    __syncthreads();

    // scan 784 bins: thread t owns bins [4t, 4t+4)
    int tsum = 0;
    if (tid < NSUBMAX / 4) {
      #pragma unroll
      for (int j = 0; j < 4; ++j) tsum += cnt[4 * tid + j];
    }
    ls[tid] = tsum;
    __syncthreads();
    for (int o = 1; o < 256; o <<= 1) {
      int v = (tid >= o) ? ls[tid - o] : 0;
      __syncthreads();
      ls[tid] += v;
      __syncthreads();
    }
    const int tot = ls[255];
    if (tid < NSUBMAX / 4) {
      int b = ls[tid] - tsum;   // exclusive
      #pragma unroll
      for (int j = 0; j < 4; ++j) { lbase[4 * tid + j] = b; b += cnt[4 * tid + j]; }
    }
    __syncthreads();
    for (int i = tid; i < nsubt; i += 256) {
      const int c = cnt[i];
      gbase[i] = c ? atomicAdd(&cur2[i], c) : 0;
    }
    __syncthreads();
    #pragma unroll
    for (int k = 0; k < KE; ++k) {
      if (sd[k] >= 0) {
        const int p = lbase[sd[k]] + off[k];
        staged[p] = pk[k];
        sstage[p] = (ushort)sd[k];
      }
    }
    __syncthreads();
    for (int i = tid; i < tot; i += 256) {
      const int sid = sstage[i];
      const int p = gbase[sid] + (i - lbase[sid]);
      if (p < SCAP) bsub[(size_t)sid * SCAP + p] = staged[i];
    }
  }
}

// ---------- phase B: per sub-bucket counting sort; emits dinv, rowinfo, dense csr ----------
__global__ __launch_bounds__(256) void k_fill3(const int* __restrict__ bsub, const int* __restrict__ cur2,
                                               float* __restrict__ dinv, uint4* __restrict__ rowinfo,
                                               int* __restrict__ csr, int N) {
  __shared__ int cnt[128], pre[128], lcur[128];
  __shared__ int stage[SCAP], sorted[SCAP];
  const int tid = threadIdx.x;
  const int sid = blockIdx.x;
  const int gn0 = sid * 128;
  int nodes = N - gn0; if (nodes > 128) nodes = 128;
  if (nodes <= 0) return;
  if (tid < 128) cnt[tid] = 0;
  __syncthreads();

  const int slotbase = sid * SCAP;
  const int cc = min(cur2[sid], SCAP);
  const int* bp = bsub + (size_t)slotbase;
  for (int i = tid; i < cc; i += 256) {
    const int v = bp[i];
    stage[i] = v;
    atomicAdd(&cnt[v & 127], 1);
  }
  __syncthreads();

  // exclusive scan of cnt[128]
  if (tid < 128) pre[tid] = cnt[tid];
  __syncthreads();
  for (int off = 1; off < 128; off <<= 1) {
    int v = 0;
    if (tid < 128 && tid >= off) v = pre[tid - off];
    __syncthreads();
    if (tid < 128) pre[tid] += v;
    __syncthreads();
  }
  if (tid < 128) pre[tid] -= cnt[tid];
  __syncthreads();

  // per-node outputs
  if (tid < nodes) {
    const int c = cnt[tid];
    const float dv = rsqrtf((float)(1 + c));
    dinv[gn0 + tid] = dv;
    rowinfo[gn0 + tid] = make_uint4((uint)(slotbase + pre[tid]), (uint)c, __float_as_uint(dv), 0u);
    lcur[tid] = pre[tid];
  }
  __syncthreads();

  // counting sort stage -> sorted (src values)
  for (int i = tid; i < cc; i += 256) {
    const int v = stage[i];
    const int p = atomicAdd(&lcur[v & 127], 1);
    sorted[p] = (int)((unsigned)v >> 7);
  }
  __syncthreads();
  for (int i = tid; i < cc; i += 256) csr[slotbase + i] = sorted[i];
}

// ---------- aggregation: one node per 16-lane group; per-message dinv[s] fma ----------
#define ACCS(q, ds) { a0 = fmaf(bflo((q).x), ds, a0); a1 = fmaf(bfhi((q).x), ds, a1); \
                      a2 = fmaf(bflo((q).y), ds, a2); a3 = fmaf(bfhi((q).y), ds, a3); \
                      a4 = fmaf(bflo((q).z), ds, a4); a5 = fmaf(bfhi((q).z), ds, a5); \
                      a6 = fmaf(bflo((q).w), ds, a6); a7 = fmaf(bfhi((q).w), ds, a7); }
__global__ __launch_bounds__(256) void k_agg(const ushort* __restrict__ hs, const float* __restrict__ dinv,
                                             const uint4* __restrict__ rowinfo, const int* __restrict__ csr,
                                             const float* __restrict__ bias, float* __restrict__ out, int N) {
  const int d = blockIdx.x * 16 + (threadIdx.x >> 4);
  if (d >= N) return;
  const int j = threadIdx.x & 15;
  const uint4* hp = (const uint4*)hs;

  const uint4 info = rowinfo[d];
  int i = (int)info.x;
  int cnt = (int)info.y;
  const float dd = __uint_as_float(info.z);

  // self message: h[d]*dinv[d] (then *dd at the end)
  const uint4 qs = hp[(size_t)d * 16 + j];
  float a0 = bflo(qs.x) * dd, a1 = bfhi(qs.x) * dd, a2 = bflo(qs.y) * dd, a3 = bfhi(qs.y) * dd;
  float a4 = bflo(qs.z) * dd, a5 = bfhi(qs.z) * dd, a6 = bflo(qs.w) * dd, a7 = bfhi(qs.w) * dd;

  for (; cnt >= 8; cnt -= 8, i += 8) {
    const int s0 = csr[i],     s1 = csr[i + 1], s2 = csr[i + 2], s3 = csr[i + 3];
    const int s4 = csr[i + 4], s5 = csr[i + 5], s6 = csr[i + 6], s7 = csr[i + 7];
    const float d0 = dinv[s0], d1 = dinv[s1], d2 = dinv[s2], d3 = dinv[s3];
    const float d4 = dinv[s4], d5 = dinv[s5], d6 = dinv[s6], d7 = dinv[s7];
    const uint4 qA = hp[(size_t)s0 * 16 + j];
    const uint4 qB = hp[(size_t)s1 * 16 + j];
    const uint4 qC = hp[(size_t)s2 * 16 + j];
    const uint4 qD = hp[(size_t)s3 * 16 + j];
    const uint4 qE = hp[(size_t)s4 * 16 + j];
    const uint4 qF = hp[(size_t)s5 * 16 + j];
    const uint4 qG = hp[(size_t)s6 * 16 + j];
    const uint4 qH = hp[(size_t)s7 * 16 + j];
    ACCS(qA, d0) ACCS(qB, d1) ACCS(qC, d2) ACCS(qD, d3)
    ACCS(qE, d4) ACCS(qF, d5) ACCS(qG, d6) ACCS(qH, d7)
  }
  if (cnt >= 4) {
    const int s0 = csr[i], s1 = csr[i + 1], s2 = csr[i + 2], s3 = csr[i + 3];
    const float d0 = dinv[s0], d1 = dinv[s1], d2 = dinv[s2], d3 = dinv[s3];
    const uint4 qA = hp[(size_t)s0 * 16 + j];
    const uint4 qB = hp[(size_t)s1 * 16 + j];
    const uint4 qC = hp[(size_t)s2 * 16 + j];
    const uint4 qD = hp[(size_t)s3 * 16 + j];
    ACCS(qA, d0) ACCS(qB, d1) ACCS(qC, d2) ACCS(qD, d3)
    cnt -= 4; i += 4;
  }
  for (; cnt > 0; --cnt, ++i) {
    const int s = csr[i];
    const float ds = dinv[s];
    const uint4 q = hp[(size_t)s * 16 + j];
    ACCS(q, ds)
  }

  const float4_t b0 = *(const float4_t*)(bias + j * 8);
  const float4_t b1 = *(const float4_t*)(bias + j * 8 + 4);
  float4_t o0, o1;
  o0.x = a0 * dd + b0.x; o0.y = a1 * dd + b0.y; o0.z = a2 * dd + b0.z; o0.w = a3 * dd + b0.w;
  o1.x = a4 * dd + b1.x; o1.y = a5 * dd + b1.y; o1.z = a6 * dd + b1.z; o1.w = a7 * dd + b1.w;
  __builtin_nontemporal_store(o0, (float4_t*)(out + (size_t)d * H + j * 8));
  __builtin_nontemporal_store(o1, (float4_t*)(out + (size_t)d * H + j * 8 + 4));
}

extern "C" void kernel_launch(void* const* d_in, const int* in_sizes, int n_in,
                              void* d_out, int out_size, void* d_ws, size_t ws_size,
                              hipStream_t stream) {
  const float* x = (const float*)d_in[0];
  const int*   edge = (const int*)d_in[1];
  const float* W = (const float*)d_in[2];
  const float* b = (const float*)d_in[3];
  float* out = (float*)d_out;

  const int N = in_sizes[0] / H;     // 100000
  const int E = in_sizes[1] / 2;     // 1600000
  const int* src = edge;
  const int* dst = edge + E;
  const int nsubt = (N + 127) / 128;                // 782

  // workspace layout
  char* w = (char*)d_ws;
  ushort* hs     = (ushort*)w;  w += (size_t)N * H * 2;              // 25.6 MB
  float*  dinv   = (float*)w;   w += (size_t)N * 4;
  int*    cur2   = (int*)w;     w += (size_t)NSUBMAX * 4;
  uint4*  rowinfo= (uint4*)w;   w += (size_t)N * 16;                 // 1.6 MB
  int*    csr    = (int*)w;     w += (size_t)nsubt * SCAP * 4;       // 9.6 MB
  int*    bsub   = (int*)w;     w += (size_t)nsubt * SCAP * 4;       // 9.6 MB
  (void)ws_size;

  (void)hipMemsetAsync(cur2, 0, (size_t)NSUBMAX * 4, stream);

  const int nbin = (E + TILE - 1) / TILE;          // 391
  k_linbin<<<LINB + nbin, 256, 0, stream>>>(x, W, hs, src, dst, cur2, bsub, N, E, nsubt);
  k_fill3<<<nsubt, 256, 0, stream>>>(bsub, cur2, dinv, rowinfo, csr, N);
  k_agg<<<(N + 15) / 16, 256, 0, stream>>>(hs, dinv, rowinfo, csr, b, out, N);
}